// Round 9
// baseline (197.019 us; speedup 1.0000x reference)
//
#include <hip/hip_runtime.h>
#include <hip/hip_bf16.h>

// FeatureAdaption R9: R8 (32x32x16 MFMA + K-split(2) partials) with the
// grid-decomposition bug fixed: 512 blocks = 8b x 32hp x 2khalf (R8 launched
// 1024 and decoded b in [0,16) -> memory corruption).
// conv1(256->256) -> conv2(256->72)=offsets -> deform conv v1 + ReLU.
// B=8, C=256, H=W=64, dg=4, K=9 taps, K_total=2304.

typedef __attribute__((ext_vector_type(8))) short bf16x8;
typedef __attribute__((ext_vector_type(16))) float f32x16;

static __device__ __forceinline__ ushort f2bf(float f) {
  __hip_bfloat16 h = __float2bfloat16(f);
  return *reinterpret_cast<ushort*>(&h);
}
static __device__ __forceinline__ float bf2f(ushort u) {
  union { uint u32; float f; } cv;
  cv.u32 = ((uint)u) << 16;
  return cv.f;
}
static __device__ __forceinline__ int swq(int co) {       // swizzle key
  return ((co & 7) + ((co >> 3) & 3)) & 7;
}

// ---------------- weight prep: swizzled 32x32-ready tiles ----------------
// Tile layout [ti][co][p(8)][e(8)]: stored = orig[co][ ti*64 + (p^swq(co))*8 + e ]
// conv  : ti = kk*4 + chunk  (ci = chunk*64 + cc)
// deform: ti = g*9 + kk      (c = cc within group)
__global__ __launch_bounds__(256) void prep_weights(
    const float* __restrict__ w1, const float* __restrict__ w2,
    const float* __restrict__ wd,
    ushort* __restrict__ wt1s, ushort* __restrict__ wt2s,
    ushort* __restrict__ wtds) {
  const int N1 = 36 * 256 * 64;   // 589824
  const int N2 = 36 * 96 * 64;    // 221184 (co padded 72->96)
  const int N3 = 36 * 256 * 64;   // 589824
  int total = N1 + N2 + N3;
  for (int i = blockIdx.x * 256 + threadIdx.x; i < total; i += gridDim.x * 256) {
    if (i < N1) {
      int e = i & 7, p = (i >> 3) & 7, co = (i >> 6) & 255, ti = i >> 14;
      int cc = ((p ^ swq(co)) << 3) + e;
      int kk = ti >> 2, chunk = ti & 3;
      wt1s[i] = f2bf(w1[(co * 256 + chunk * 64 + cc) * 9 + kk]);
    } else if (i < N1 + N2) {
      int d = i - N1;
      int e = d & 7, p = (d >> 3) & 7;
      int r = d >> 6;
      int co = r % 96, ti = r / 96;
      int cc = ((p ^ swq(co)) << 3) + e;
      int kk = ti >> 2, chunk = ti & 3;
      wt2s[d] = (co < 72) ? f2bf(w2[(co * 256 + chunk * 64 + cc) * 9 + kk])
                          : (ushort)0;
    } else {
      int d = i - N1 - N2;
      int e = d & 7, p = (d >> 3) & 7, co = (d >> 6) & 255, ti = d >> 14;
      int c = ((p ^ swq(co)) << 3) + e;
      int g = ti / 9, kk = ti - g * 9;
      wtds[d] = f2bf(wd[(co * 256 + g * 64 + c) * 9 + kk]);
    }
  }
}

// ---------------- x -> channel-last grouped bf16 (verified R3-R7) ----------------
__global__ __launch_bounds__(256) void transpose_x(
    const float* __restrict__ x, ushort* __restrict__ xt) {
  int id = blockIdx.x;
  int y = id & 63, bg = id >> 6;
  int c = threadIdx.x & 63, xi = threadIdx.x >> 6;
  const float* ip = x + (((size_t)bg) << 18) + ((size_t)c << 12) + y * 64;
  ushort* op = xt + (((size_t)bg) << 18) + (size_t)y * 4096 + c;
#pragma unroll
  for (int j = 0; j < 16; ++j) {
    int xx = xi * 16 + j;
    op[(size_t)xx * 64] = f2bf(ip[xx]);
  }
}

// ---------------- unified 32x32 MFMA kernel, K-split partials ----------------
// Block = (b, h-pair, khalf): 4 waves x 32px = 128 px (2 rows), full-N co tile,
// 18 K-tiles of 64. A row=lane&31 (px), B col=lane&31 (co).
// C/D: col=lane&31 (co), row=(reg&3)+8*(reg>>2)+4*(lane>>5) (px) [m74/m101].
// CHLAST par: [bg][px4096][c64] bf16; planar par: [(b*COW+co)*4096+px] bf16.
template <int MODE, int NFR, bool CHLAST>
__global__ __launch_bounds__(256, 2) void fa_mfma7(
    const ushort* __restrict__ inT,  // [bg][4096 px][64 c] bf16
    const float* __restrict__ off,   // [B][72][64][64] f32 (MODE 1)
    const char* __restrict__ wBs,    // swizzled tiles [36][CO_TILE*128 B]
    ushort* __restrict__ parA,       // partial half 0
    ushort* __restrict__ parB,       // partial half 1
    int co_write) {
  constexpr int CO_TILE = NFR * 32;
  constexpr int TILE_B = CO_TILE * 128;            // bytes per K-tile
  constexpr int NCALLS = TILE_B / 4096;            // 16B x 256thr per call
  __shared__ __align__(16) ushort Blds[2][CO_TILE * 64];

  int id = blockIdx.x;
  int id2 = (id & 7) * 64 + (id >> 3);             // XCD swizzle (512 = 8*64)
  int khalf = id2 & 1;
  int rest = id2 >> 1;                             // 0..255
  int hp = rest & 31, b = rest >> 5;               // h-pair [0,32), batch [0,8)
  int h0 = hp * 2;
  int t = threadIdx.x;
  int wv = t >> 6, lane = t & 63;
  int c31 = lane & 31, kc2 = lane >> 5;
  int qr = swq(c31);
  int pxl = wv * 32 + c31;                         // lane's pixel in block
  int row = h0 + (pxl >> 6), col = pxl & 63;
  ushort* par = khalf ? parB : parA;

  auto stage = [&](int tloc, int bufsel) {
    const char* src0 = wBs + (size_t)(khalf * 18 + tloc) * TILE_B + t * 16;
    ushort* dst0 = &Blds[bufsel][t * 8];
#pragma unroll
    for (int m = 0; m < NCALLS; ++m) {
      __builtin_amdgcn_global_load_lds(
          (const __attribute__((address_space(1))) void*)(src0 + m * 4096),
          (__attribute__((address_space(3))) void*)(dst0 + m * 2048), 16, 0, 0);
    }
  };

  f32x16 acc[NFR];
#pragma unroll
  for (int j = 0; j < NFR; ++j)
#pragma unroll
    for (int r = 0; r < 16; ++r) acc[j][r] = 0.f;

  const bf16x8 bz = {0, 0, 0, 0, 0, 0, 0, 0};

  // ---------------- MODE 0: direct conv ----------------
  if (MODE == 0) {
    bf16x8 rN[4];
    auto issueA0 = [&](int tg) {
      int kk = tg >> 2, ch = tg & 3;
      int ky = kk / 3, kx = kk - ky * 3;
      int gy = row + ky - 1, gx = col + kx - 1;
      bool inb = (gy >= 0) & (gy < 64) & (gx >= 0) & (gx < 64);
      const ushort* p =
          inT + ((((size_t)(b * 4 + ch) << 12) + gy * 64 + gx) << 6) + kc2 * 8;
#pragma unroll
      for (int ks = 0; ks < 4; ++ks)
        rN[ks] = inb ? *(const bf16x8*)(p + ks * 16) : bz;
    };

    issueA0(khalf * 18);
    stage(0, 0);
    __syncthreads();

    for (int tloc = 0; tloc < 18; ++tloc) {
      int cur = tloc & 1;
      bf16x8 aC[4];
#pragma unroll
      for (int ks = 0; ks < 4; ++ks) aC[ks] = rN[ks];
      if (tloc < 17) {
        stage(tloc + 1, cur ^ 1);
        issueA0(khalf * 18 + tloc + 1);
      }
#pragma unroll
      for (int ks = 0; ks < 4; ++ks) {
        int slot = ((2 * ks + kc2) ^ qr) << 3;
#pragma unroll
        for (int nf = 0; nf < NFR; ++nf) {
          bf16x8 bq = *(const bf16x8*)&Blds[cur][(nf * 32 + c31) * 64 + slot];
          acc[nf] = __builtin_amdgcn_mfma_f32_32x32x16_bf16(aC[ks], bq, acc[nf], 0, 0, 0);
        }
      }
      if (tloc < 17) __syncthreads();
    }
  } else {
    // ---------------- MODE 1: deformable ----------------
    uint oC[4];
    float wC[4];
    const ushort* plC;
    float2 offN;
    bf16x8 rN[8];

    auto loadOff = [&](int tg) {
      int g = tg / 9, kk = tg - 9 * (tg / 9);
      const float* offp =
          off + (((size_t)b * 72 + g * 18 + kk * 2) << 12) + row * 64 + col;
      offN.x = offp[0];
      offN.y = offp[4096];
    };
    auto calcAddr = [&](int tg, float2 oa, uint* o4, float* w4,
                        const ushort*& pl) {
      int g = tg / 9, kk = tg - 9 * (tg / 9);
      int ky = kk / 3, kx = kk - ky * 3;
      float py = (float)(row + ky - 1) + oa.x;
      float pxf = (float)(col + kx - 1) + oa.y;
      float y0f = floorf(py), x0f = floorf(pxf);
      float wy1 = py - y0f, wx1 = pxf - x0f;
      float wy0 = 1.f - wy1, wx0 = 1.f - wx1;
      int y0 = (int)y0f, x0i = (int)x0f;
      int y1 = y0 + 1, x1i = x0i + 1;
      bool vy0 = (y0 >= 0) & (y0 < 64);
      bool vy1 = (y1 >= 0) & (y1 < 64);
      bool vx0 = (x0i >= 0) & (x0i < 64);
      bool vx1 = (x1i >= 0) & (x1i < 64);
      w4[0] = (vy0 & vx0) ? wy0 * wx0 : 0.f;
      w4[1] = (vy0 & vx1) ? wy0 * wx1 : 0.f;
      w4[2] = (vy1 & vx0) ? wy1 * wx0 : 0.f;
      w4[3] = (vy1 & vx1) ? wy1 * wx1 : 0.f;
      int yc0 = min(max(y0, 0), 63), yc1 = min(max(y1, 0), 63);
      int xc0 = min(max(x0i, 0), 63), xc1 = min(max(x1i, 0), 63);
      o4[0] = (uint)((yc0 * 64 + xc0) << 6);
      o4[1] = (uint)((yc0 * 64 + xc1) << 6);
      o4[2] = (uint)((yc1 * 64 + xc0) << 6);
      o4[3] = (uint)((yc1 * 64 + xc1) << 6);
      pl = inT + (((size_t)(b * 4 + g)) << 18) + kc2 * 8;
    };
    auto gather = [&](const ushort* pl, const uint* o4, int hs) {
#pragma unroll
      for (int cr = 0; cr < 4; ++cr) {
        rN[cr * 2] = *(const bf16x8*)(pl + o4[cr] + (hs * 2) * 16);
        rN[cr * 2 + 1] = *(const bf16x8*)(pl + o4[cr] + (hs * 2 + 1) * 16);
      }
    };
    auto finish = [&](const float* w4, bf16x8& a0, bf16x8& a1) {
#pragma unroll
      for (int ksl = 0; ksl < 2; ++ksl) {
        bf16x8 q0 = rN[0 + ksl], q1 = rN[2 + ksl], q2 = rN[4 + ksl], q3 = rN[6 + ksl];
        bf16x8 av;
#pragma unroll
        for (int e = 0; e < 8; ++e) {
          float v = w4[0] * bf2f((ushort)q0[e]) + w4[1] * bf2f((ushort)q1[e]) +
                    w4[2] * bf2f((ushort)q2[e]) + w4[3] * bf2f((ushort)q3[e]);
          av[e] = (short)f2bf(v);
        }
        if (ksl == 0) a0 = av; else a1 = av;
      }
    };

    // prologue
    loadOff(khalf * 18);
    calcAddr(khalf * 18, offN, oC, wC, plC);
    gather(plC, oC, 0);                            // h0 of tile 0
    loadOff(khalf * 18 + 1);
    stage(0, 0);
    __syncthreads();

    for (int tloc = 0; tloc < 18; ++tloc) {
      int tg = khalf * 18 + tloc;
      int cur = tloc & 1;
      if (tloc < 17) stage(tloc + 1, cur ^ 1);

      bf16x8 a0, a1;
      finish(wC, a0, a1);                          // half 0 (ks 0,1)
      gather(plC, oC, 1);                          // issue half 1 gathers
#pragma unroll
      for (int ks = 0; ks < 2; ++ks) {
        int slot = ((2 * ks + kc2) ^ qr) << 3;
        bf16x8 a = ks ? a1 : a0;
#pragma unroll
        for (int nf = 0; nf < NFR; ++nf) {
          bf16x8 bq = *(const bf16x8*)&Blds[cur][(nf * 32 + c31) * 64 + slot];
          acc[nf] = __builtin_amdgcn_mfma_f32_32x32x16_bf16(a, bq, acc[nf], 0, 0, 0);
        }
      }

      uint oN[4];
      float wN[4];
      const ushort* plN = plC;
      if (tloc < 17) calcAddr(tg + 1, offN, oN, wN, plN);
      if (tloc < 16) loadOff(tg + 2);

      finish(wC, a0, a1);                          // half 1 (ks 2,3)
      if (tloc < 17) gather(plN, oN, 0);           // issue h0 of next tile
#pragma unroll
      for (int ks = 2; ks < 4; ++ks) {
        int slot = ((2 * ks + kc2) ^ qr) << 3;
        bf16x8 a = (ks == 2) ? a0 : a1;
#pragma unroll
        for (int nf = 0; nf < NFR; ++nf) {
          bf16x8 bq = *(const bf16x8*)&Blds[cur][(nf * 32 + c31) * 64 + slot];
          acc[nf] = __builtin_amdgcn_mfma_f32_32x32x16_bf16(a, bq, acc[nf], 0, 0, 0);
        }
      }

      if (tloc < 17) {
#pragma unroll
        for (int cr = 0; cr < 4; ++cr) { oC[cr] = oN[cr]; wC[cr] = wN[cr]; }
        plC = plN;
        __syncthreads();
      }
    }
  }

  // ---- epilogue: write bf16 partials ----
#pragma unroll
  for (int nf = 0; nf < NFR; ++nf) {
    int cog = nf * 32 + c31;
    if (cog < co_write) {
#pragma unroll
      for (int r = 0; r < 16; ++r) {
        int pxb = wv * 32 + (r & 3) + 8 * (r >> 2) + 4 * kc2;
        ushort v = f2bf(acc[nf][r]);
        if (CHLAST) {
          par[((((size_t)(b * 4 + (cog >> 6)) << 12) + h0 * 64 + pxb) << 6) +
              (cog & 63)] = v;
        } else {
          par[(((size_t)b * co_write + cog) << 12) + h0 * 64 + pxb] = v;
        }
      }
    }
  }
}

// ---------------- reduce kernels ----------------
// conv1: chlast p0+p1 + bias -> bf16 chlast t1
__global__ __launch_bounds__(256) void reduce_c1(
    const ushort* __restrict__ p0, const ushort* __restrict__ p1,
    const float* __restrict__ bias, ushort* __restrict__ t1) {
  const int N8 = (8 * 4 * 4096 * 64) / 8;
  for (int i = blockIdx.x * 256 + threadIdx.x; i < N8; i += gridDim.x * 256) {
    size_t base = (size_t)i * 8;
    bf16x8 a = *(const bf16x8*)(p0 + base);
    bf16x8 c = *(const bf16x8*)(p1 + base);
    int c0 = (int)(base & 63);
    int g = (int)((base >> 18) & 3);
    bf16x8 o;
#pragma unroll
    for (int j = 0; j < 8; ++j) {
      float v = bf2f((ushort)a[j]) + bf2f((ushort)c[j]) + bias[g * 64 + c0 + j];
      o[j] = (short)f2bf(v);
    }
    *(bf16x8*)(t1 + base) = o;
  }
}

// conv2: planar p0+p1 + bias -> f32 offsets
__global__ __launch_bounds__(256) void reduce_c2(
    const ushort* __restrict__ p0, const ushort* __restrict__ p1,
    const float* __restrict__ bias, float* __restrict__ out) {
  const int N8 = (8 * 72 * 4096) / 8;
  for (int i = blockIdx.x * 256 + threadIdx.x; i < N8; i += gridDim.x * 256) {
    size_t base = (size_t)i * 8;
    bf16x8 a = *(const bf16x8*)(p0 + base);
    bf16x8 c = *(const bf16x8*)(p1 + base);
    int co = (int)((base >> 12) % 72);
    float bv = bias[co];
    float4 o0, o1;
    o0.x = bf2f((ushort)a[0]) + bf2f((ushort)c[0]) + bv;
    o0.y = bf2f((ushort)a[1]) + bf2f((ushort)c[1]) + bv;
    o0.z = bf2f((ushort)a[2]) + bf2f((ushort)c[2]) + bv;
    o0.w = bf2f((ushort)a[3]) + bf2f((ushort)c[3]) + bv;
    o1.x = bf2f((ushort)a[4]) + bf2f((ushort)c[4]) + bv;
    o1.y = bf2f((ushort)a[5]) + bf2f((ushort)c[5]) + bv;
    o1.z = bf2f((ushort)a[6]) + bf2f((ushort)c[6]) + bv;
    o1.w = bf2f((ushort)a[7]) + bf2f((ushort)c[7]) + bv;
    *(float4*)(out + base) = o0;
    *(float4*)(out + base + 4) = o1;
  }
}

// deform: chlast p0+p1 -> relu -> f32 planar NCHW (LDS-transposed tiles)
__global__ __launch_bounds__(256) void reduce_df(
    const ushort* __restrict__ p0, const ushort* __restrict__ p1,
    float* __restrict__ out) {
  __shared__ float ts[64][65];
  int bid = blockIdx.x;                  // 2048 = 8b * 4cq * 64pt
  int pt = bid & 63, cq = (bid >> 6) & 3, b = bid >> 8;
  int t = threadIdx.x;
  int c = t & 63, ty = t >> 6;
  size_t inbase = (((size_t)(b * 4 + cq) << 12) + pt * 64) << 6;
#pragma unroll 4
  for (int s = 0; s < 16; ++s) {
    int pxi = ty * 16 + s;
    size_t idx = inbase + ((size_t)pxi << 6) + c;
    float v = bf2f(p0[idx]) + bf2f(p1[idx]);
    ts[c][pxi] = fmaxf(v, 0.f);
  }
  __syncthreads();
  int px = t & 63;
#pragma unroll 4
  for (int s = 0; s < 16; ++s) {
    int coi = ty * 16 + s;
    out[(((size_t)b * 256 + cq * 64 + coi) << 12) + pt * 64 + px] = ts[coi][px];
  }
}

extern "C" void kernel_launch(void* const* d_in, const int* in_sizes, int n_in,
                              void* d_out, int out_size, void* d_ws, size_t ws_size,
                              hipStream_t stream) {
  const float* x  = (const float*)d_in[0];
  const float* w1 = (const float*)d_in[1];
  const float* b1 = (const float*)d_in[2];
  const float* w2 = (const float*)d_in[3];
  const float* b2 = (const float*)d_in[4];
  const float* wd = (const float*)d_in[5];

  char* wsb = (char*)d_ws;
  float*  off_buf = (float*)wsb;                    //  9,437,184 B
  ushort* xt      = (ushort*)(wsb + 9437184);       // 16,777,216 B
  ushort* wt1s    = (ushort*)(wsb + 26214400);      //  1,179,648 B
  ushort* wt2s    = (ushort*)(wsb + 27394048);      //    442,368 B
  ushort* wtds    = (ushort*)(wsb + 27836416);      //  1,179,648 B
  ushort* par0    = (ushort*)(wsb + 29016064);      // 16,777,216 B
  ushort* par1    = (ushort*)(wsb + 45793280);      // 16,777,216 B -> 62.6 MB

  prep_weights<<<2048, 256, 0, stream>>>(w1, w2, wd, wt1s, wt2s, wtds);
  transpose_x<<<2048, 256, 0, stream>>>(x, xt);

  ushort* t1 = (ushort*)d_out;   // bf16 chlast t1 lives in d_out until deform

  // conv1: xt -> partials (chlast), CO_TILE=256
  fa_mfma7<0, 8, true><<<512, 256, 0, stream>>>(
      xt, nullptr, (const char*)wt1s, par0, par1, 256);
  reduce_c1<<<2048, 256, 0, stream>>>(par0, par1, b1, t1);

  // conv2: t1 -> partials (planar, co<72), CO_TILE=96
  fa_mfma7<0, 3, false><<<512, 256, 0, stream>>>(
      t1, nullptr, (const char*)wt2s, par0, par1, 72);
  reduce_c2<<<1024, 256, 0, stream>>>(par0, par1, b2, off_buf);

  // deform: xt + offsets -> partials (chlast), CO_TILE=256
  fa_mfma7<1, 8, true><<<512, 256, 0, stream>>>(
      xt, off_buf, (const char*)wtds, par0, par1, 256);
  reduce_df<<<2048, 256, 0, stream>>>(par0, par1, (float*)d_out);
}